// Round 3
// baseline (596.347 us; speedup 1.0000x reference)
//
#include <hip/hip_runtime.h>
#include <hip/hip_bf16.h>
#include <cfloat>

// Problem constants
#define B_   8
#define C_   256
#define CR_  128
#define T_   16
#define HW_  784
#define THW_ 12544           // T_*HW_
#define N_   1024            // B_*CR_
#define KTOP 196

typedef __attribute__((ext_vector_type(8))) short short8;
typedef __attribute__((ext_vector_type(8))) _Float16 half8;
typedef __attribute__((ext_vector_type(4))) float float4_;

// bf16 helpers (RN-even), header-independent
__device__ __forceinline__ unsigned short f2bf(float x) {
    unsigned int u = __float_as_uint(x);
    unsigned int r = u + 0x7fffu + ((u >> 16) & 1u);
    return (unsigned short)(r >> 16);
}
__device__ __forceinline__ float bf2f(unsigned short s) {
    return __uint_as_float(((unsigned int)s) << 16);
}
// fp16 split: v = hi + lo to 22 mantissa bits
__device__ __forceinline__ void splith(float v, unsigned short& h, unsigned short& l) {
    _Float16 hh = (_Float16)v;
    _Float16 ll = (_Float16)(v - (float)hh);
    h = __builtin_bit_cast(unsigned short, hh);
    l = __builtin_bit_cast(unsigned short, ll);
}

// ---------------------------------------------------------------------------
// Kernel 0: prep.
//  - W16  [o=384][k=256] fp16 of {Wq,Wk,Wv} (native k-major)
//  - Wrbf [co=256][cr=128] bf16 of Wr (native k-major)
//  - bias3[384] = bq|bk|bv
//  - A1[co]=gamma*rsqrt(var+eps), A2[co]=br*A1 + beta - mean*A1
// ---------------------------------------------------------------------------
__global__ __launch_bounds__(256) void prep(
    const float* __restrict__ Wq, const float* __restrict__ Wk,
    const float* __restrict__ Wv, const float* __restrict__ Wr,
    const float* __restrict__ bq, const float* __restrict__ bk,
    const float* __restrict__ bv, const float* __restrict__ br,
    const float* __restrict__ gamma, const float* __restrict__ beta,
    const float* __restrict__ bn_mean, const float* __restrict__ bn_var,
    unsigned short* __restrict__ W16,
    unsigned short* __restrict__ Wrbf, float* __restrict__ bias3,
    float* __restrict__ A1, float* __restrict__ A2)
{
    int idx = blockIdx.x * 256 + threadIdx.x;
    if (idx < 384 * 256) {
        int o = idx >> 8, k = idx & 255;
        int m = o >> 7, r = o & 127;
        const float* W = (m == 0) ? Wq : (m == 1) ? Wk : Wv;
        float v = W[r * 256 + k];
        _Float16 hh = (_Float16)v;
        W16[idx] = __builtin_bit_cast(unsigned short, hh);
    }
    if (idx < 256 * 128) {
        Wrbf[idx] = f2bf(Wr[idx]);
    }
    if (idx < 384) {
        bias3[idx] = (idx < 128) ? bq[idx] : (idx < 256) ? bk[idx - 128] : bv[idx - 256];
    }
    if (idx < 256) {
        float sc = gamma[idx] * rsqrtf(bn_var[idx] + 1e-5f);
        A1[idx] = sc;
        A2[idx] = br[idx] * sc + beta[idx] - bn_mean[idx] * sc;
    }
}

// ---------------------------------------------------------------------------
// Kernel 1: QKV GEMM via fp16x2 MFMA (fp32-accurate input split; W in fp16,
// rel err 2^-12 -> ~2e-4 on outputs, invisible vs bf16-class downstream).
// out[b,o,p] = sum_c W[o,c] x[b,c,p] + bias[o],  o in [0,384)
//
// v4: A staged in LDS once per BLOCK (was per-wave global scatter: 512B-stride
// dwordx4 = 16 lines/instr saturated the TA/L2 request path; three prior
// variants all pinned at 157us / 15% MfmaUtil).
//  - M split 2x: block = 192 rows x 64 p, 256 threads / 4 waves of 48x64.
//  - A [2][192][40] fp16 (30.7KB) + B [2][2][64][40] (20.5KB) = 51.2KB LDS
//    -> 3 blocks/CU (12 waves). Padded rows: conflict-free ds_read_b128.
//  - fp16x2: 24 MFMA/wave/k-step (was 36), single A matrix (was hi+lo).
//  - One barrier per k-step; next-step loads issued before the MFMA cluster.
// grid (196, 2, 8): (p-tile, m-block, batch)
// ---------------------------------------------------------------------------
__global__ __launch_bounds__(256, 3) void gemm_qkv_mfma(
    const unsigned short* __restrict__ W16,
    const float* __restrict__ x, const float* __restrict__ bias3,
    float* __restrict__ Qb, float* __restrict__ Kb, float* __restrict__ Vb)
{
    const int tid  = threadIdx.x;
    const int wave = tid >> 6;
    const int lane = tid & 63;
    const int quad = lane >> 4;
    const int l16  = lane & 15;
    const int p0   = blockIdx.x * 64;
    const int Mb   = blockIdx.y * 192;
    const int b    = blockIdx.z;
    const int mW   = wave * 48;

    // A: [buf][row=192][k=32 pad->40]; B: [buf][var hi/lo][p=64][k=32 pad->40]
    __shared__ unsigned short Ald[2][192][40];
    __shared__ unsigned short Bld[2][2][64][40];

    float4_ acc[3][4];
#pragma unroll
    for (int i = 0; i < 3; i++)
#pragma unroll
        for (int j = 0; j < 4; j++) acc[i][j] = (float4_)0.f;

    const float* xb = x + (size_t)b * C_ * THW_;
    const unsigned short* Wb = W16 + (size_t)Mb * 256;
    const int sp = lane;        // staged p (coalesced across lanes)
    const int kg = wave * 8;    // staged k-group (8 k per thread)

    // prologue: stage k-step 0 into buf 0
    {
#pragma unroll
        for (int it = 0; it < 3; it++) {
            int c = tid + it * 256, row = c >> 2, j = c & 3;
            *(uint4*)&Ald[0][row][j * 8] = *(const uint4*)&Wb[(size_t)row * 256 + j * 8];
        }
        float f[8];
#pragma unroll
        for (int j = 0; j < 8; j++)
            f[j] = xb[(size_t)(kg + j) * THW_ + p0 + sp];
        short8 h8, l8;
#pragma unroll
        for (int j = 0; j < 8; j++) {
            unsigned short hh, ll; splith(f[j], hh, ll);
            h8[j] = (short)hh; l8[j] = (short)ll;
        }
        *(short8*)&Bld[0][0][sp][kg] = h8;
        *(short8*)&Bld[0][1][sp][kg] = l8;
    }
    __syncthreads();

#pragma unroll 2
    for (int ks = 0; ks < 8; ks++) {
        const int cur = ks & 1;
        const int k0n = (ks + 1) * 32;

        // issue next-step global loads early (latency hides under MFMA)
        uint4 au[3];
        float f[8];
        if (ks < 7) {
#pragma unroll
            for (int it = 0; it < 3; it++) {
                int c = tid + it * 256, row = c >> 2, j = c & 3;
                au[it] = *(const uint4*)&Wb[(size_t)row * 256 + k0n + j * 8];
            }
#pragma unroll
            for (int j = 0; j < 8; j++)
                f[j] = xb[(size_t)(k0n + kg + j) * THW_ + p0 + sp];
        }

        // B fragments from LDS (split already done)
        short8 Bh[4], Bl[4];
#pragma unroll
        for (int nf = 0; nf < 4; nf++) {
            Bh[nf] = *(const short8*)&Bld[cur][0][nf * 16 + l16][quad * 8];
            Bl[nf] = *(const short8*)&Bld[cur][1][nf * 16 + l16][quad * 8];
        }

        // MFMA: 3 m-frags x 4 n-frags x 2 products (fp16x2)
#pragma unroll
        for (int mf = 0; mf < 3; mf++) {
            half8 Af = *(const half8*)&Ald[cur][mW + mf * 16 + l16][quad * 8];
#pragma unroll
            for (int nf = 0; nf < 4; nf++) {
                acc[mf][nf] = __builtin_amdgcn_mfma_f32_16x16x32_f16(
                    Af, *(const half8*)&Bl[nf], acc[mf][nf], 0, 0, 0);
                acc[mf][nf] = __builtin_amdgcn_mfma_f32_16x16x32_f16(
                    Af, *(const half8*)&Bh[nf], acc[mf][nf], 0, 0, 0);
            }
        }

        // write next tile into the other buffer (waits on the early loads)
        if (ks < 7) {
#pragma unroll
            for (int it = 0; it < 3; it++) {
                int c = tid + it * 256, row = c >> 2, j = c & 3;
                *(uint4*)&Ald[cur ^ 1][row][j * 8] = au[it];
            }
            short8 h8, l8;
#pragma unroll
            for (int j = 0; j < 8; j++) {
                unsigned short hh, ll; splith(f[j], hh, ll);
                h8[j] = (short)hh; l8[j] = (short)ll;
            }
            *(short8*)&Bld[cur ^ 1][0][sp][kg] = h8;
            *(short8*)&Bld[cur ^ 1][1][sp][kg] = l8;
        }
        __syncthreads();
    }

    // --- epilogue: o = Mb + mW + mf*16 + quad*4 + r, p = p0 + nf*16 + l16 ---
#pragma unroll
    for (int mf = 0; mf < 3; mf++) {
#pragma unroll
        for (int r = 0; r < 4; r++) {
            int oo  = Mb + mW + mf * 16 + quad * 4 + r;
            int mat = oo >> 7;
            int cr  = oo & 127;
            float bi = bias3[oo];
            float* dst = ((mat == 0) ? Qb : (mat == 1) ? Kb : Vb)
                         + ((size_t)(b * 128 + cr)) * THW_ + p0 + l16;
#pragma unroll
            for (int nf = 0; nf < 4; nf++)
                dst[nf * 16] = acc[mf][nf][r] + bi;
        }
    }
}

// ---------------------------------------------------------------------------
// Kernel 2: per-row descending bitonic sort, fully in registers.
// TWO rows per wave: 32 lanes per row, 32 elements per lane.
// ---------------------------------------------------------------------------
__global__ __launch_bounds__(256) void topk_sort_wave(
    const float* __restrict__ Qb, const float* __restrict__ Kb,
    float* __restrict__ Qtk, float* __restrict__ Ktk)
{
    const int wave = threadIdx.x >> 6;
    const int lane = threadIdx.x & 63;
    const int half = lane >> 5;
    const int L    = lane & 31;
    const int gw   = (blockIdx.x * 4 + wave) * 2 + half;   // 0..32767
    const int mat  = gw >> 14;                             // 0: Q, 1: K
    const int row  = gw & 16383;
    const float* src = ((mat == 0) ? Qb : Kb) + (size_t)row * HW_;
    float* dst       = ((mat == 0) ? Qtk : Ktk) + (size_t)row * KTOP;

    float v[32];
    if (L < 24) {
        const float4* s4 = (const float4*)(src + L * 32);
#pragma unroll
        for (int q = 0; q < 8; q++) {
            float4 t = s4[q];
            v[q * 4 + 0] = t.x; v[q * 4 + 1] = t.y;
            v[q * 4 + 2] = t.z; v[q * 4 + 3] = t.w;
        }
    } else if (L == 24) {
        const float4* s4 = (const float4*)(src + 768);
#pragma unroll
        for (int q = 0; q < 4; q++) {
            float4 t = s4[q];
            v[q * 4 + 0] = t.x; v[q * 4 + 1] = t.y;
            v[q * 4 + 2] = t.z; v[q * 4 + 3] = t.w;
        }
#pragma unroll
        for (int r = 16; r < 32; r++) v[r] = -FLT_MAX;
    } else {
#pragma unroll
        for (int r = 0; r < 32; r++) v[r] = -FLT_MAX;
    }

#pragma unroll
    for (int k = 2; k <= 1024; k <<= 1) {
#pragma unroll
        for (int j = k >> 1; j >= 1; j >>= 1) {
            if (j >= 32) {
                const int jl = j >> 5;                      // 1..16, within 32-half
                const bool up      = ((L & (k >> 5)) == 0); // k >= 64 here
                const bool isLower = ((L & jl) == 0);
                const bool keepMax = (up == isLower);
#pragma unroll
                for (int r = 0; r < 32; r++) {
                    float other = __shfl_xor(v[r], jl, 64);
                    float mx = fmaxf(v[r], other);
                    float mn = fminf(v[r], other);
                    v[r] = keepMax ? mx : mn;
                }
            } else {
#pragma unroll
                for (int r = 0; r < 32; r++) {
                    if ((r & j) == 0) {
                        const int rb = r | j;
                        const bool up = (k >= 32) ? ((L & (k >> 5)) == 0)
                                                  : ((r & k) == 0);
                        float a = v[r], b = v[rb];
                        float hi = fmaxf(a, b), lo = fminf(a, b);
                        v[r]  = up ? hi : lo;
                        v[rb] = up ? lo : hi;
                    }
                }
            }
        }
    }

    // top-196 sorted descending: elements 0..195 -> L<6 full, L==6 first 4
    if (L < 6) {
        float4* d4 = (float4*)(dst + L * 32);
#pragma unroll
        for (int q = 0; q < 8; q++) {
            float4 t;
            t.x = v[q * 4 + 0]; t.y = v[q * 4 + 1];
            t.z = v[q * 4 + 2]; t.w = v[q * 4 + 3];
            d4[q] = t;
        }
    } else if (L == 6) {
        float4 t;
        t.x = v[0]; t.y = v[1]; t.z = v[2]; t.w = v[3];
        *(float4*)(dst + 192) = t;
    }
}

// ---------------------------------------------------------------------------
// Kernel 3: corr + softmax (unchanged).
// ---------------------------------------------------------------------------
__global__ __launch_bounds__(256) void corr_softmax(
    const float* __restrict__ Qtk, const float* __restrict__ Ktk,
    float* __restrict__ attn)
{
    const int n = blockIdx.x;
    __shared__ float qs[T_ * KTOP];
    __shared__ float ks[T_ * KTOP];
    __shared__ float cm[T_][T_ + 1];
    __shared__ float mx[T_], sm[T_];
    const int tid = threadIdx.x;

    for (int i = tid; i < T_ * KTOP; i += 256) {
        qs[i] = Qtk[(size_t)n * T_ * KTOP + i];
        ks[i] = Ktk[(size_t)n * T_ * KTOP + i];
    }
    __syncthreads();

    const int t = tid >> 4, sidx = tid & 15;
    const float* qr = &qs[t * KTOP];
    const float* kr = &ks[sidx * KTOP];
    float c = 0.f;
#pragma unroll 4
    for (int i = 0; i < KTOP; i++) c += qr[i] * kr[i];
    cm[t][sidx] = c;
    __syncthreads();

    if (tid < T_) {
        float m = cm[tid][0];
        for (int i = 1; i < T_; i++) m = fmaxf(m, cm[tid][i]);
        mx[tid] = m;
    }
    __syncthreads();
    float e = expf(c - mx[t]);
    cm[t][sidx] = e;
    __syncthreads();
    if (tid < T_) {
        float ssum = 0.f;
        for (int i = 0; i < T_; i++) ssum += cm[tid][i];
        sm[tid] = ssum;
    }
    __syncthreads();
    attn[(size_t)n * 256 + tid] = e / sm[t];
}

// ---------------------------------------------------------------------------
// Kernel 4: apply attention, output TRANSPOSED bf16: yT[b][t*784+p][cr].
// grid (49, 8): (p-window of 16, batch). cr processed in chunks of 16.
// ---------------------------------------------------------------------------
__global__ __launch_bounds__(256) void apply_attn_T(
    const float* __restrict__ attn, const float* __restrict__ V,
    unsigned short* __restrict__ yT)
{
    const int pc = blockIdx.x;      // p-window
    const int b  = blockIdx.y;
    const int p0 = pc * 16;
    const int tid = threadIdx.x;
    const int crl = tid & 15;       // local cr
    const int g   = tid >> 4;       // t index (0..15)

    __shared__ float at[16][257];   // [crl][t*16+s]
    __shared__ float vt[16][260];   // [crl][s*16+p], 16B-aligned rows

    for (int chunk = 0; chunk < 8; chunk++) {
        const int crbase = chunk * 16;
        for (int i = tid; i < 16 * 256; i += 256) {
            int cr = i >> 8, ts = i & 255;
            at[cr][ts] = attn[((size_t)(b * 128 + crbase + cr)) * 256 + ts];
        }
        for (int i = tid; i < 16 * 256; i += 256) {
            int cr = i >> 8, s = (i >> 4) & 15, p = i & 15;
            vt[cr][s * 16 + p] =
                V[((size_t)(b * 128 + crbase + cr)) * THW_ + s * HW_ + p0 + p];
        }
        __syncthreads();

        const int cr = crbase + crl;
        float a[16];
#pragma unroll
        for (int s = 0; s < 16; s++) a[s] = at[crl][g * 16 + s];
        float sum[16];
#pragma unroll
        for (int p = 0; p < 16; p++) sum[p] = 0.f;
#pragma unroll
        for (int s = 0; s < 16; s++) {
            const float as = a[s];
#pragma unroll
            for (int p4 = 0; p4 < 4; p4++) {
                float4 vv = *(const float4*)&vt[crl][s * 16 + p4 * 4];
                sum[p4 * 4 + 0] += as * vv.x;
                sum[p4 * 4 + 1] += as * vv.y;
                sum[p4 * 4 + 2] += as * vv.z;
                sum[p4 * 4 + 3] += as * vv.w;
            }
        }
        const size_t obase = (size_t)b * THW_ + (size_t)g * HW_ + p0;
#pragma unroll
        for (int p = 0; p < 16; p++)
            yT[(obase + p) * 128 + cr] = f2bf(sum[p]);
        __syncthreads();
    }
}

// ---------------------------------------------------------------------------
// Kernel 5: reconstruct GEMM via bf16 MFMA, fused BN + residual (unchanged).
// grid (196, 8)
// ---------------------------------------------------------------------------
__global__ __launch_bounds__(256) void gemm_recon_mfma(
    const unsigned short* __restrict__ Wrbf, const unsigned short* __restrict__ yT,
    const float* __restrict__ A1, const float* __restrict__ A2,
    const float* __restrict__ x, float* __restrict__ out)
{
    const int tid  = threadIdx.x;
    const int wave = tid >> 6;
    const int lane = tid & 63;
    const int quad = lane >> 4;
    const int l16  = lane & 15;
    const int p0   = blockIdx.x * 64;
    const int b    = blockIdx.y;
    const int mW   = wave * 64;

    float4_ acc[4][4];
#pragma unroll
    for (int i = 0; i < 4; i++)
#pragma unroll
        for (int j = 0; j < 4; j++) acc[i][j] = (float4_)0.f;

    const unsigned short* yTb = yT + (size_t)b * THW_ * 128;

#pragma unroll
    for (int k0 = 0; k0 < 128; k0 += 32) {
        short8 Bf[4];
#pragma unroll
        for (int nf = 0; nf < 4; nf++)
            Bf[nf] = *(const short8*)&yTb[(size_t)(p0 + nf * 16 + l16) * 128 + k0 + quad * 8];
#pragma unroll
        for (int mf = 0; mf < 4; mf++) {
            short8 Af = *(const short8*)&Wrbf[(size_t)(mW + mf * 16 + l16) * 128 + k0 + quad * 8];
#pragma unroll
            for (int nf = 0; nf < 4; nf++)
                acc[mf][nf] = __builtin_amdgcn_mfma_f32_16x16x32_bf16(Af, Bf[nf], acc[mf][nf], 0, 0, 0);
        }
    }

#pragma unroll
    for (int mf = 0; mf < 4; mf++) {
#pragma unroll
        for (int r = 0; r < 4; r++) {
            int co = mW + mf * 16 + quad * 4 + r;
            float sc = A1[co], sh = A2[co];
            size_t base = ((size_t)b * 256 + co) * THW_ + p0 + l16;
#pragma unroll
            for (int nf = 0; nf < 4; nf++) {
                float xv = x[base + nf * 16];
                out[base + nf * 16] = acc[mf][nf][r] * sc + sh + xv;
            }
        }
    }
}

// ---------------------------------------------------------------------------
extern "C" void kernel_launch(void* const* d_in, const int* in_sizes, int n_in,
                              void* d_out, int out_size, void* d_ws, size_t ws_size,
                              hipStream_t stream)
{
    const float* x      = (const float*)d_in[0];
    const float* Wq     = (const float*)d_in[1];
    const float* bq     = (const float*)d_in[2];
    const float* Wk     = (const float*)d_in[3];
    const float* bk     = (const float*)d_in[4];
    const float* Wv     = (const float*)d_in[5];
    const float* bv     = (const float*)d_in[6];
    const float* Wr     = (const float*)d_in[7];
    const float* br     = (const float*)d_in[8];
    const float* gamma  = (const float*)d_in[9];
    const float* beta   = (const float*)d_in[10];
    const float* bn_mean= (const float*)d_in[11];
    const float* bn_var = (const float*)d_in[12];
    float* out = (float*)d_out;

    // d_out doubles as scratch for Q and K (exactly 2 * N_*THW_ floats)
    float* Qb = out;
    float* Kb = out + (size_t)N_ * THW_;

    // workspace layout
    char* ws = (char*)d_ws;
    float* Vb            = (float*)ws;                       ws += (size_t)N_ * THW_ * 4;      // 51.4 MB
    unsigned short* yT   = (unsigned short*)ws;              ws += (size_t)N_ * THW_ * 2;      // 25.7 MB
    float* Qtk           = (float*)ws;                       ws += (size_t)N_ * T_ * KTOP * 4;
    float* Ktk           = (float*)ws;                       ws += (size_t)N_ * T_ * KTOP * 4;
    float* attn          = (float*)ws;                       ws += (size_t)N_ * T_ * T_ * 4;
    unsigned short* W16  = (unsigned short*)ws;              ws += 384 * 256 * 2;
    unsigned short* Wrbf = (unsigned short*)ws;              ws += 256 * 128 * 2;
    float* bias3         = (float*)ws;                       ws += 384 * 4;
    float* A1            = (float*)ws;                       ws += 256 * 4;
    float* A2            = (float*)ws;                       ws += 256 * 4;

    prep<<<dim3(384), 256, 0, stream>>>(Wq, Wk, Wv, Wr, bq, bk, bv, br,
                                        gamma, beta, bn_mean, bn_var,
                                        W16, Wrbf, bias3, A1, A2);
    gemm_qkv_mfma<<<dim3(196, 2, 8), 256, 0, stream>>>(W16, x, bias3, Qb, Kb, Vb);
    topk_sort_wave<<<dim3(4096), 256, 0, stream>>>(Qb, Kb, Qtk, Ktk);
    corr_softmax<<<dim3(1024), 256, 0, stream>>>(Qtk, Ktk, attn);
    apply_attn_T<<<dim3(49, 8), 256, 0, stream>>>(attn, Vb, yT);
    gemm_recon_mfma<<<dim3(196, 8), 256, 0, stream>>>(Wrbf, yT, A1, A2, x, out);
}

// Round 10
// 497.047 us; speedup vs baseline: 1.1998x; 1.1998x over previous
//
#include <hip/hip_runtime.h>
#include <hip/hip_bf16.h>
#include <cfloat>

// Problem constants
#define B_   8
#define C_   256
#define CR_  128
#define T_   16
#define HW_  784
#define THW_ 12544           // T_*HW_
#define N_   1024            // B_*CR_
#define KTOP 196

typedef __attribute__((ext_vector_type(8))) short short8;
typedef __attribute__((ext_vector_type(8))) _Float16 half8;
typedef __attribute__((ext_vector_type(4))) float float4_;

// bf16 helpers (RN-even), header-independent
__device__ __forceinline__ unsigned short f2bf(float x) {
    unsigned int u = __float_as_uint(x);
    unsigned int r = u + 0x7fffu + ((u >> 16) & 1u);
    return (unsigned short)(r >> 16);
}
__device__ __forceinline__ float bf2f(unsigned short s) {
    return __uint_as_float(((unsigned int)s) << 16);
}
// fp16 split: v = hi + lo to 22 mantissa bits
__device__ __forceinline__ void splith(float v, unsigned short& h, unsigned short& l) {
    _Float16 hh = (_Float16)v;
    _Float16 ll = (_Float16)(v - (float)hh);
    h = __builtin_bit_cast(unsigned short, hh);
    l = __builtin_bit_cast(unsigned short, ll);
}

// ---------------------------------------------------------------------------
// Kernel 0: prep.
//  - W16  [o=384][k=256] fp16 of {Wq,Wk,Wv} (native k-major)
//  - Wrbf [co=256][cr=128] bf16 of Wr (native k-major)
//  - bias3[384] = bq|bk|bv
//  - A1[co]=gamma*rsqrt(var+eps), A2[co]=br*A1 + beta - mean*A1
// ---------------------------------------------------------------------------
__global__ __launch_bounds__(256) void prep(
    const float* __restrict__ Wq, const float* __restrict__ Wk,
    const float* __restrict__ Wv, const float* __restrict__ Wr,
    const float* __restrict__ bq, const float* __restrict__ bk,
    const float* __restrict__ bv, const float* __restrict__ br,
    const float* __restrict__ gamma, const float* __restrict__ beta,
    const float* __restrict__ bn_mean, const float* __restrict__ bn_var,
    unsigned short* __restrict__ W16,
    unsigned short* __restrict__ Wrbf, float* __restrict__ bias3,
    float* __restrict__ A1, float* __restrict__ A2)
{
    int idx = blockIdx.x * 256 + threadIdx.x;
    if (idx < 384 * 256) {
        int o = idx >> 8, k = idx & 255;
        int m = o >> 7, r = o & 127;
        const float* W = (m == 0) ? Wq : (m == 1) ? Wk : Wv;
        float v = W[r * 256 + k];
        _Float16 hh = (_Float16)v;
        W16[idx] = __builtin_bit_cast(unsigned short, hh);
    }
    if (idx < 256 * 128) {
        Wrbf[idx] = f2bf(Wr[idx]);
    }
    if (idx < 384) {
        bias3[idx] = (idx < 128) ? bq[idx] : (idx < 256) ? bk[idx - 128] : bv[idx - 256];
    }
    if (idx < 256) {
        float sc = gamma[idx] * rsqrtf(bn_var[idx] + 1e-5f);
        A1[idx] = sc;
        A2[idx] = br[idx] * sc + beta[idx] - bn_mean[idx] * sc;
    }
}

// ---------------------------------------------------------------------------
// Kernel 1: QKV GEMM via fp16x2 MFMA.
// out[b,o,p] = sum_c W[o,c] x[b,c,p] + bias[o],  o in [0,384)
//
// v5: byte-minimal + r3's proven staging structure.
//  - SINGLE pass over x (no m-split): full 384-row A tile in LDS.
//    (r3's m-split doubled HBM traffic: FETCH 56->114MB, WRITE 154->285MB.)
//  - A double-buffered [2][384][36] fp16, 72B rows (8B-aligned b64-pair
//    fragment reads); B double-buffered [2][2][64][40] hi/lo split.
//    LDS 75.8KB -> 2 blocks/CU; ONE barrier per k-step.
//  - 512 threads / 8 waves of 48x64; 24 MFMA/wave/k-step.
//  - Next-step global loads issued before the MFMA cluster.
// grid (196, 8): (p-tile of 64, batch)
// ---------------------------------------------------------------------------
__global__ __launch_bounds__(512, 4) void gemm_qkv_mfma(
    const unsigned short* __restrict__ W16,
    const float* __restrict__ x, const float* __restrict__ bias3,
    float* __restrict__ Qb, float* __restrict__ Kb, float* __restrict__ Vb)
{
    const int tid  = threadIdx.x;
    const int wave = tid >> 6;
    const int lane = tid & 63;
    const int quad = lane >> 4;
    const int l16  = lane & 15;
    const int p0   = blockIdx.x * 64;
    const int b    = blockIdx.y;
    const int mW   = wave * 48;

    // A: [buf][row=384][k=32, 72B rows]; B: [buf][var hi/lo][p=64][k=32 pad->40]
    __shared__ unsigned short Ald[2][384][36];
    __shared__ unsigned short Bld[2][2][64][40];

    float4_ acc[3][4];
#pragma unroll
    for (int i = 0; i < 3; i++)
#pragma unroll
        for (int j = 0; j < 4; j++) acc[i][j] = (float4_)0.f;

    const float* xb = x + (size_t)b * C_ * THW_;
    const int sp  = lane;        // staged p (coalesced across lanes)
    const int kgB = wave * 4;    // staged k-group for B (4 k per thread)

    // prologue: stage k-step 0 into buf 0
    {
#pragma unroll
        for (int it = 0; it < 6; it++) {
            int c = tid + it * 512, row = c >> 3, part = c & 7;
            *(uint2*)&Ald[0][row][part * 4] =
                *(const uint2*)&W16[(size_t)row * 256 + part * 4];
        }
        float f[4];
#pragma unroll
        for (int j = 0; j < 4; j++)
            f[j] = xb[(size_t)(kgB + j) * THW_ + p0 + sp];
#pragma unroll
        for (int j = 0; j < 4; j++) {
            unsigned short hh, ll; splith(f[j], hh, ll);
            Bld[0][0][sp][kgB + j] = hh;
            Bld[0][1][sp][kgB + j] = ll;
        }
    }
    __syncthreads();

#pragma unroll 2
    for (int ks = 0; ks < 8; ks++) {
        const int cur = ks & 1;
        const int k0n = (ks + 1) * 32;

        // issue next-step global loads early (latency hides under MFMA)
        uint2 au[6];
        float f[4];
        if (ks < 7) {
#pragma unroll
            for (int it = 0; it < 6; it++) {
                int c = tid + it * 512, row = c >> 3, part = c & 7;
                au[it] = *(const uint2*)&W16[(size_t)row * 256 + k0n + part * 4];
            }
#pragma unroll
            for (int j = 0; j < 4; j++)
                f[j] = xb[(size_t)(k0n + kgB + j) * THW_ + p0 + sp];
        }

        // B fragments from LDS (split already done)
        short8 Bh[4], Bl[4];
#pragma unroll
        for (int nf = 0; nf < 4; nf++) {
            Bh[nf] = *(const short8*)&Bld[cur][0][nf * 16 + l16][quad * 8];
            Bl[nf] = *(const short8*)&Bld[cur][1][nf * 16 + l16][quad * 8];
        }

        // MFMA: 3 m-frags x 4 n-frags x 2 products (fp16x2)
#pragma unroll
        for (int mf = 0; mf < 3; mf++) {
            const unsigned short* ap = &Ald[cur][mW + mf * 16 + l16][quad * 8];
            half8 Af;
            *(uint2*)&Af       = *(const uint2*)ap;        // shorts 0..3
            *((uint2*)&Af + 1) = *(const uint2*)(ap + 4);  // shorts 4..7
#pragma unroll
            for (int nf = 0; nf < 4; nf++) {
                acc[mf][nf] = __builtin_amdgcn_mfma_f32_16x16x32_f16(
                    Af, *(const half8*)&Bl[nf], acc[mf][nf], 0, 0, 0);
                acc[mf][nf] = __builtin_amdgcn_mfma_f32_16x16x32_f16(
                    Af, *(const half8*)&Bh[nf], acc[mf][nf], 0, 0, 0);
            }
        }

        // write next tile into the other buffer (waits on the early loads)
        if (ks < 7) {
#pragma unroll
            for (int it = 0; it < 6; it++) {
                int c = tid + it * 512, row = c >> 3, part = c & 7;
                *(uint2*)&Ald[cur ^ 1][row][part * 4] = au[it];
            }
#pragma unroll
            for (int j = 0; j < 4; j++) {
                unsigned short hh, ll; splith(f[j], hh, ll);
                Bld[cur ^ 1][0][sp][kgB + j] = hh;
                Bld[cur ^ 1][1][sp][kgB + j] = ll;
            }
        }
        __syncthreads();
    }

    // --- epilogue: o = mW + mf*16 + quad*4 + r, p = p0 + nf*16 + l16 ---
#pragma unroll
    for (int mf = 0; mf < 3; mf++) {
#pragma unroll
        for (int r = 0; r < 4; r++) {
            int oo  = mW + mf * 16 + quad * 4 + r;
            int mat = oo >> 7;
            int cr  = oo & 127;
            float bi = bias3[oo];
            float* dst = ((mat == 0) ? Qb : (mat == 1) ? Kb : Vb)
                         + ((size_t)(b * 128 + cr)) * THW_ + p0 + l16;
#pragma unroll
            for (int nf = 0; nf < 4; nf++)
                dst[nf * 16] = acc[mf][nf][r] + bi;
        }
    }
}

// ---------------------------------------------------------------------------
// Kernel 2: per-row descending bitonic sort, fully in registers.
// TWO rows per wave: 32 lanes per row, 32 elements per lane.
// ---------------------------------------------------------------------------
__global__ __launch_bounds__(256) void topk_sort_wave(
    const float* __restrict__ Qb, const float* __restrict__ Kb,
    float* __restrict__ Qtk, float* __restrict__ Ktk)
{
    const int wave = threadIdx.x >> 6;
    const int lane = threadIdx.x & 63;
    const int half = lane >> 5;
    const int L    = lane & 31;
    const int gw   = (blockIdx.x * 4 + wave) * 2 + half;   // 0..32767
    const int mat  = gw >> 14;                             // 0: Q, 1: K
    const int row  = gw & 16383;
    const float* src = ((mat == 0) ? Qb : Kb) + (size_t)row * HW_;
    float* dst       = ((mat == 0) ? Qtk : Ktk) + (size_t)row * KTOP;

    float v[32];
    if (L < 24) {
        const float4* s4 = (const float4*)(src + L * 32);
#pragma unroll
        for (int q = 0; q < 8; q++) {
            float4 t = s4[q];
            v[q * 4 + 0] = t.x; v[q * 4 + 1] = t.y;
            v[q * 4 + 2] = t.z; v[q * 4 + 3] = t.w;
        }
    } else if (L == 24) {
        const float4* s4 = (const float4*)(src + 768);
#pragma unroll
        for (int q = 0; q < 4; q++) {
            float4 t = s4[q];
            v[q * 4 + 0] = t.x; v[q * 4 + 1] = t.y;
            v[q * 4 + 2] = t.z; v[q * 4 + 3] = t.w;
        }
#pragma unroll
        for (int r = 16; r < 32; r++) v[r] = -FLT_MAX;
    } else {
#pragma unroll
        for (int r = 0; r < 32; r++) v[r] = -FLT_MAX;
    }

#pragma unroll
    for (int k = 2; k <= 1024; k <<= 1) {
#pragma unroll
        for (int j = k >> 1; j >= 1; j >>= 1) {
            if (j >= 32) {
                const int jl = j >> 5;                      // 1..16, within 32-half
                const bool up      = ((L & (k >> 5)) == 0); // k >= 64 here
                const bool isLower = ((L & jl) == 0);
                const bool keepMax = (up == isLower);
#pragma unroll
                for (int r = 0; r < 32; r++) {
                    float other = __shfl_xor(v[r], jl, 64);
                    float mx = fmaxf(v[r], other);
                    float mn = fminf(v[r], other);
                    v[r] = keepMax ? mx : mn;
                }
            } else {
#pragma unroll
                for (int r = 0; r < 32; r++) {
                    if ((r & j) == 0) {
                        const int rb = r | j;
                        const bool up = (k >= 32) ? ((L & (k >> 5)) == 0)
                                                  : ((r & k) == 0);
                        float a = v[r], b = v[rb];
                        float hi = fmaxf(a, b), lo = fminf(a, b);
                        v[r]  = up ? hi : lo;
                        v[rb] = up ? lo : hi;
                    }
                }
            }
        }
    }

    // top-196 sorted descending: elements 0..195 -> L<6 full, L==6 first 4
    if (L < 6) {
        float4* d4 = (float4*)(dst + L * 32);
#pragma unroll
        for (int q = 0; q < 8; q++) {
            float4 t;
            t.x = v[q * 4 + 0]; t.y = v[q * 4 + 1];
            t.z = v[q * 4 + 2]; t.w = v[q * 4 + 3];
            d4[q] = t;
        }
    } else if (L == 6) {
        float4 t;
        t.x = v[0]; t.y = v[1]; t.z = v[2]; t.w = v[3];
        *(float4*)(dst + 192) = t;
    }
}

// ---------------------------------------------------------------------------
// Kernel 3: corr + softmax (unchanged).
// ---------------------------------------------------------------------------
__global__ __launch_bounds__(256) void corr_softmax(
    const float* __restrict__ Qtk, const float* __restrict__ Ktk,
    float* __restrict__ attn)
{
    const int n = blockIdx.x;
    __shared__ float qs[T_ * KTOP];
    __shared__ float ks[T_ * KTOP];
    __shared__ float cm[T_][T_ + 1];
    __shared__ float mx[T_], sm[T_];
    const int tid = threadIdx.x;

    for (int i = tid; i < T_ * KTOP; i += 256) {
        qs[i] = Qtk[(size_t)n * T_ * KTOP + i];
        ks[i] = Ktk[(size_t)n * T_ * KTOP + i];
    }
    __syncthreads();

    const int t = tid >> 4, sidx = tid & 15;
    const float* qr = &qs[t * KTOP];
    const float* kr = &ks[sidx * KTOP];
    float c = 0.f;
#pragma unroll 4
    for (int i = 0; i < KTOP; i++) c += qr[i] * kr[i];
    cm[t][sidx] = c;
    __syncthreads();

    if (tid < T_) {
        float m = cm[tid][0];
        for (int i = 1; i < T_; i++) m = fmaxf(m, cm[tid][i]);
        mx[tid] = m;
    }
    __syncthreads();
    float e = expf(c - mx[t]);
    cm[t][sidx] = e;
    __syncthreads();
    if (tid < T_) {
        float ssum = 0.f;
        for (int i = 0; i < T_; i++) ssum += cm[tid][i];
        sm[tid] = ssum;
    }
    __syncthreads();
    attn[(size_t)n * 256 + tid] = e / sm[t];
}

// ---------------------------------------------------------------------------
// Kernel 4: apply attention, output TRANSPOSED bf16: yT[b][t*784+p][cr].
// grid (49, 8): (p-window of 16, batch). cr processed in chunks of 16.
// ---------------------------------------------------------------------------
__global__ __launch_bounds__(256) void apply_attn_T(
    const float* __restrict__ attn, const float* __restrict__ V,
    unsigned short* __restrict__ yT)
{
    const int pc = blockIdx.x;      // p-window
    const int b  = blockIdx.y;
    const int p0 = pc * 16;
    const int tid = threadIdx.x;
    const int crl = tid & 15;       // local cr
    const int g   = tid >> 4;       // t index (0..15)

    __shared__ float at[16][257];   // [crl][t*16+s]
    __shared__ float vt[16][260];   // [crl][s*16+p], 16B-aligned rows

    for (int chunk = 0; chunk < 8; chunk++) {
        const int crbase = chunk * 16;
        for (int i = tid; i < 16 * 256; i += 256) {
            int cr = i >> 8, ts = i & 255;
            at[cr][ts] = attn[((size_t)(b * 128 + crbase + cr)) * 256 + ts];
        }
        for (int i = tid; i < 16 * 256; i += 256) {
            int cr = i >> 8, s = (i >> 4) & 15, p = i & 15;
            vt[cr][s * 16 + p] =
                V[((size_t)(b * 128 + crbase + cr)) * THW_ + s * HW_ + p0 + p];
        }
        __syncthreads();

        const int cr = crbase + crl;
        float a[16];
#pragma unroll
        for (int s = 0; s < 16; s++) a[s] = at[crl][g * 16 + s];
        float sum[16];
#pragma unroll
        for (int p = 0; p < 16; p++) sum[p] = 0.f;
#pragma unroll
        for (int s = 0; s < 16; s++) {
            const float as = a[s];
#pragma unroll
            for (int p4 = 0; p4 < 4; p4++) {
                float4 vv = *(const float4*)&vt[crl][s * 16 + p4 * 4];
                sum[p4 * 4 + 0] += as * vv.x;
                sum[p4 * 4 + 1] += as * vv.y;
                sum[p4 * 4 + 2] += as * vv.z;
                sum[p4 * 4 + 3] += as * vv.w;
            }
        }
        const size_t obase = (size_t)b * THW_ + (size_t)g * HW_ + p0;
#pragma unroll
        for (int p = 0; p < 16; p++)
            yT[(obase + p) * 128 + cr] = f2bf(sum[p]);
        __syncthreads();
    }
}

// ---------------------------------------------------------------------------
// Kernel 5: reconstruct GEMM via bf16 MFMA, fused BN + residual.
//
// v2.1: LDS-staged operands; FIX of v2's Wld staging indexing (was
// row=c>>3/part=c&7 — wrote rows 0..255 OOB and left cols 64..127 stale,
// NaN via uninitialized LDS). Correct: 128 rows x 16 uint4/row.
//  - co-split: block = 128 co x 64 p; Wld 34.8KB + Yld 17.4KB = 52.2KB LDS
//    -> 3 blocks/CU.
// grid (196, 2, 8): (p-tile, co-half, batch)
// ---------------------------------------------------------------------------
__global__ __launch_bounds__(256, 3) void gemm_recon_mfma(
    const unsigned short* __restrict__ Wrbf, const unsigned short* __restrict__ yT,
    const float* __restrict__ A1, const float* __restrict__ A2,
    const float* __restrict__ x, float* __restrict__ out)
{
    const int tid  = threadIdx.x;
    const int wave = tid >> 6;
    const int lane = tid & 63;
    const int quad = lane >> 4;
    const int l16  = lane & 15;
    const int p0   = blockIdx.x * 64;
    const int coB  = blockIdx.y * 128;
    const int b    = blockIdx.z;
    const int mW   = wave * 32;

    __shared__ unsigned short Wld[128][136];   // 272B rows (17x16B)
    __shared__ unsigned short Yld[64][136];

    // stage Wrbf half: 128 rows x 128 shorts = 32KB = 2048 uint4
    // (16 uint4 per row: row = c>>4, part = c&15)
#pragma unroll
    for (int it = 0; it < 8; it++) {
        int c = tid + it * 256, row = c >> 4, part = c & 15;
        *(uint4*)&Wld[row][part * 8] =
            *(const uint4*)&Wrbf[(size_t)(coB + row) * 128 + part * 8];
    }
    // stage yT tile: 64 contiguous thw-rows x 128 shorts = 16KB (1024 uint4)
    const unsigned short* yTb = yT + ((size_t)b * THW_ + p0) * 128;
#pragma unroll
    for (int it = 0; it < 4; it++) {
        int c = tid + it * 256, row = c >> 4, part = c & 15;
        *(uint4*)&Yld[row][part * 8] =
            *(const uint4*)&yTb[(size_t)row * 128 + part * 8];
    }
    __syncthreads();

    float4_ acc[2][4];
#pragma unroll
    for (int i = 0; i < 2; i++)
#pragma unroll
        for (int j = 0; j < 4; j++) acc[i][j] = (float4_)0.f;

#pragma unroll
    for (int k0 = 0; k0 < 128; k0 += 32) {
        short8 Bf[4];
#pragma unroll
        for (int nf = 0; nf < 4; nf++)
            Bf[nf] = *(const short8*)&Yld[nf * 16 + l16][k0 + quad * 8];
#pragma unroll
        for (int mf = 0; mf < 2; mf++) {
            short8 Af = *(const short8*)&Wld[mW + mf * 16 + l16][k0 + quad * 8];
#pragma unroll
            for (int nf = 0; nf < 4; nf++)
                acc[mf][nf] = __builtin_amdgcn_mfma_f32_16x16x32_bf16(Af, Bf[nf], acc[mf][nf], 0, 0, 0);
        }
    }

#pragma unroll
    for (int mf = 0; mf < 2; mf++) {
#pragma unroll
        for (int r = 0; r < 4; r++) {
            int co = coB + mW + mf * 16 + quad * 4 + r;
            float sc = A1[co], sh = A2[co];
            size_t base = ((size_t)b * 256 + co) * THW_ + p0 + l16;
#pragma unroll
            for (int nf = 0; nf < 4; nf++) {
                float xv = x[base + nf * 16];
                out[base + nf * 16] = acc[mf][nf][r] * sc + sh + xv;
            }
        }
    }
}

// ---------------------------------------------------------------------------
extern "C" void kernel_launch(void* const* d_in, const int* in_sizes, int n_in,
                              void* d_out, int out_size, void* d_ws, size_t ws_size,
                              hipStream_t stream)
{
    const float* x      = (const float*)d_in[0];
    const float* Wq     = (const float*)d_in[1];
    const float* bq     = (const float*)d_in[2];
    const float* Wk     = (const float*)d_in[3];
    const float* bk     = (const float*)d_in[4];
    const float* Wv     = (const float*)d_in[5];
    const float* bv     = (const float*)d_in[6];
    const float* Wr     = (const float*)d_in[7];
    const float* br     = (const float*)d_in[8];
    const float* gamma  = (const float*)d_in[9];
    const float* beta   = (const float*)d_in[10];
    const float* bn_mean= (const float*)d_in[11];
    const float* bn_var = (const float*)d_in[12];
    float* out = (float*)d_out;

    // d_out doubles as scratch for Q and K (exactly 2 * N_*THW_ floats)
    float* Qb = out;
    float* Kb = out + (size_t)N_ * THW_;

    // workspace layout
    char* ws = (char*)d_ws;
    float* Vb            = (float*)ws;                       ws += (size_t)N_ * THW_ * 4;      // 51.4 MB
    unsigned short* yT   = (unsigned short*)ws;              ws += (size_t)N_ * THW_ * 2;      // 25.7 MB
    float* Qtk           = (float*)ws;                       ws += (size_t)N_ * T_ * KTOP * 4;
    float* Ktk           = (float*)ws;                       ws += (size_t)N_ * T_ * KTOP * 4;
    float* attn          = (float*)ws;                       ws += (size_t)N_ * T_ * T_ * 4;
    unsigned short* W16  = (unsigned short*)ws;              ws += 384 * 256 * 2;
    unsigned short* Wrbf = (unsigned short*)ws;              ws += 256 * 128 * 2;
    float* bias3         = (float*)ws;                       ws += 384 * 4;
    float* A1            = (float*)ws;                       ws += 256 * 4;
    float* A2            = (float*)ws;                       ws += 256 * 4;

    prep<<<dim3(384), 256, 0, stream>>>(Wq, Wk, Wv, Wr, bq, bk, bv, br,
                                        gamma, beta, bn_mean, bn_var,
                                        W16, Wrbf, bias3, A1, A2);
    gemm_qkv_mfma<<<dim3(196, 8), 512, 0, stream>>>(W16, x, bias3, Qb, Kb, Vb);
    topk_sort_wave<<<dim3(4096), 256, 0, stream>>>(Qb, Kb, Qtk, Ktk);
    corr_softmax<<<dim3(1024), 256, 0, stream>>>(Qtk, Ktk, attn);
    apply_attn_T<<<dim3(49, 8), 256, 0, stream>>>(attn, Vb, yT);
    gemm_recon_mfma<<<dim3(196, 2, 8), 256, 0, stream>>>(Wrbf, yT, A1, A2, x, out);
}

// Round 11
// 483.540 us; speedup vs baseline: 1.2333x; 1.0279x over previous
//
#include <hip/hip_runtime.h>
#include <hip/hip_bf16.h>
#include <cfloat>

// Problem constants
#define B_   8
#define C_   256
#define CR_  128
#define T_   16
#define HW_  784
#define THW_ 12544           // T_*HW_
#define N_   1024            // B_*CR_
#define KTOP 196

typedef __attribute__((ext_vector_type(8))) short short8;
typedef __attribute__((ext_vector_type(8))) _Float16 half8;
typedef __attribute__((ext_vector_type(4))) float float4_;

// bf16 helpers (RN-even), header-independent
__device__ __forceinline__ unsigned short f2bf(float x) {
    unsigned int u = __float_as_uint(x);
    unsigned int r = u + 0x7fffu + ((u >> 16) & 1u);
    return (unsigned short)(r >> 16);
}
__device__ __forceinline__ float bf2f(unsigned short s) {
    return __uint_as_float(((unsigned int)s) << 16);
}
// fp16 split: v = hi + lo to 22 mantissa bits
__device__ __forceinline__ void splith(float v, unsigned short& h, unsigned short& l) {
    _Float16 hh = (_Float16)v;
    _Float16 ll = (_Float16)(v - (float)hh);
    h = __builtin_bit_cast(unsigned short, hh);
    l = __builtin_bit_cast(unsigned short, ll);
}

// ---------------------------------------------------------------------------
// Kernel 0: prep.
//  - W16  [o=384][k=256] fp16 of {Wq,Wk,Wv} (native k-major)
//  - Wrbf [co=256][cr=128] bf16 of Wr (native k-major)
//  - bias3[384] = bq|bk|bv
//  - A1[co]=gamma*rsqrt(var+eps), A2[co]=br*A1 + beta - mean*A1
// ---------------------------------------------------------------------------
__global__ __launch_bounds__(256) void prep(
    const float* __restrict__ Wq, const float* __restrict__ Wk,
    const float* __restrict__ Wv, const float* __restrict__ Wr,
    const float* __restrict__ bq, const float* __restrict__ bk,
    const float* __restrict__ bv, const float* __restrict__ br,
    const float* __restrict__ gamma, const float* __restrict__ beta,
    const float* __restrict__ bn_mean, const float* __restrict__ bn_var,
    unsigned short* __restrict__ W16,
    unsigned short* __restrict__ Wrbf, float* __restrict__ bias3,
    float* __restrict__ A1, float* __restrict__ A2)
{
    int idx = blockIdx.x * 256 + threadIdx.x;
    if (idx < 384 * 256) {
        int o = idx >> 8, k = idx & 255;
        int m = o >> 7, r = o & 127;
        const float* W = (m == 0) ? Wq : (m == 1) ? Wk : Wv;
        float v = W[r * 256 + k];
        _Float16 hh = (_Float16)v;
        W16[idx] = __builtin_bit_cast(unsigned short, hh);
    }
    if (idx < 256 * 128) {
        Wrbf[idx] = f2bf(Wr[idx]);
    }
    if (idx < 384) {
        bias3[idx] = (idx < 128) ? bq[idx] : (idx < 256) ? bk[idx - 128] : bv[idx - 256];
    }
    if (idx < 256) {
        float sc = gamma[idx] * rsqrtf(bn_var[idx] + 1e-5f);
        A1[idx] = sc;
        A2[idx] = br[idx] * sc + beta[idx] - bn_mean[idx] * sc;
    }
}

// ---------------------------------------------------------------------------
// Kernel 1: QKV GEMM via fp16x2 MFMA (unchanged from r10's measured version).
// grid (196, 8): (p-tile of 64, batch)
// ---------------------------------------------------------------------------
__global__ __launch_bounds__(512, 4) void gemm_qkv_mfma(
    const unsigned short* __restrict__ W16,
    const float* __restrict__ x, const float* __restrict__ bias3,
    float* __restrict__ Qb, float* __restrict__ Kb, float* __restrict__ Vb)
{
    const int tid  = threadIdx.x;
    const int wave = tid >> 6;
    const int lane = tid & 63;
    const int quad = lane >> 4;
    const int l16  = lane & 15;
    const int p0   = blockIdx.x * 64;
    const int b    = blockIdx.y;
    const int mW   = wave * 48;

    // A: [buf][row=384][k=32, 72B rows]; B: [buf][var hi/lo][p=64][k=32 pad->40]
    __shared__ unsigned short Ald[2][384][36];
    __shared__ unsigned short Bld[2][2][64][40];

    float4_ acc[3][4];
#pragma unroll
    for (int i = 0; i < 3; i++)
#pragma unroll
        for (int j = 0; j < 4; j++) acc[i][j] = (float4_)0.f;

    const float* xb = x + (size_t)b * C_ * THW_;
    const int sp  = lane;        // staged p (coalesced across lanes)
    const int kgB = wave * 4;    // staged k-group for B (4 k per thread)

    // prologue: stage k-step 0 into buf 0
    {
#pragma unroll
        for (int it = 0; it < 6; it++) {
            int c = tid + it * 512, row = c >> 3, part = c & 7;
            *(uint2*)&Ald[0][row][part * 4] =
                *(const uint2*)&W16[(size_t)row * 256 + part * 4];
        }
        float f[4];
#pragma unroll
        for (int j = 0; j < 4; j++)
            f[j] = xb[(size_t)(kgB + j) * THW_ + p0 + sp];
#pragma unroll
        for (int j = 0; j < 4; j++) {
            unsigned short hh, ll; splith(f[j], hh, ll);
            Bld[0][0][sp][kgB + j] = hh;
            Bld[0][1][sp][kgB + j] = ll;
        }
    }
    __syncthreads();

#pragma unroll 2
    for (int ks = 0; ks < 8; ks++) {
        const int cur = ks & 1;
        const int k0n = (ks + 1) * 32;

        // issue next-step global loads early (latency hides under MFMA)
        uint2 au[6];
        float f[4];
        if (ks < 7) {
#pragma unroll
            for (int it = 0; it < 6; it++) {
                int c = tid + it * 512, row = c >> 3, part = c & 7;
                au[it] = *(const uint2*)&W16[(size_t)row * 256 + k0n + part * 4];
            }
#pragma unroll
            for (int j = 0; j < 4; j++)
                f[j] = xb[(size_t)(k0n + kgB + j) * THW_ + p0 + sp];
        }

        // B fragments from LDS (split already done)
        short8 Bh[4], Bl[4];
#pragma unroll
        for (int nf = 0; nf < 4; nf++) {
            Bh[nf] = *(const short8*)&Bld[cur][0][nf * 16 + l16][quad * 8];
            Bl[nf] = *(const short8*)&Bld[cur][1][nf * 16 + l16][quad * 8];
        }

        // MFMA: 3 m-frags x 4 n-frags x 2 products (fp16x2)
#pragma unroll
        for (int mf = 0; mf < 3; mf++) {
            const unsigned short* ap = &Ald[cur][mW + mf * 16 + l16][quad * 8];
            half8 Af;
            *(uint2*)&Af       = *(const uint2*)ap;        // shorts 0..3
            *((uint2*)&Af + 1) = *(const uint2*)(ap + 4);  // shorts 4..7
#pragma unroll
            for (int nf = 0; nf < 4; nf++) {
                acc[mf][nf] = __builtin_amdgcn_mfma_f32_16x16x32_f16(
                    Af, *(const half8*)&Bl[nf], acc[mf][nf], 0, 0, 0);
                acc[mf][nf] = __builtin_amdgcn_mfma_f32_16x16x32_f16(
                    Af, *(const half8*)&Bh[nf], acc[mf][nf], 0, 0, 0);
            }
        }

        // write next tile into the other buffer (waits on the early loads)
        if (ks < 7) {
#pragma unroll
            for (int it = 0; it < 6; it++) {
                int c = tid + it * 512, row = c >> 3, part = c & 7;
                *(uint2*)&Ald[cur ^ 1][row][part * 4] = au[it];
            }
#pragma unroll
            for (int j = 0; j < 4; j++) {
                unsigned short hh, ll; splith(f[j], hh, ll);
                Bld[cur ^ 1][0][sp][kgB + j] = hh;
                Bld[cur ^ 1][1][sp][kgB + j] = ll;
            }
        }
        __syncthreads();
    }

    // --- epilogue: o = mW + mf*16 + quad*4 + r, p = p0 + nf*16 + l16 ---
#pragma unroll
    for (int mf = 0; mf < 3; mf++) {
#pragma unroll
        for (int r = 0; r < 4; r++) {
            int oo  = mW + mf * 16 + quad * 4 + r;
            int mat = oo >> 7;
            int cr  = oo & 127;
            float bi = bias3[oo];
            float* dst = ((mat == 0) ? Qb : (mat == 1) ? Kb : Vb)
                         + ((size_t)(b * 128 + cr)) * THW_ + p0 + l16;
#pragma unroll
            for (int nf = 0; nf < 4; nf++)
                dst[nf * 16] = acc[mf][nf][r] + bi;
        }
    }
}

// ---------------------------------------------------------------------------
// Kernel 2: per-row top-196 via BITONIC TOP-K (v3).
// Was: full 1024 bitonic sort = 55 passes, ~3680 VALU elem-ops/lane,
// measured 137us @ 87% VALUBusy (pure VALU-bound).
// Now: sort four 256-blocks descending (36 passes; k=256 phase forced
// uniform-descending), then 2x [mirror-max top-256 keep + 8-pass bitonic
// merge]. Exact same top-196 output; ~2976 elem-ops (0.81x).
// Element e = L*32 + r; blocks = 8-lane groups. Mirror of the partner
// block is shfl_xor(v[31-r], 15) then (v[31-r], 23). Copy lanes do
// redundant uniform work; output (lanes 0..6) unchanged.
// ---------------------------------------------------------------------------
__global__ __launch_bounds__(256) void topk_sort_wave(
    const float* __restrict__ Qb, const float* __restrict__ Kb,
    float* __restrict__ Qtk, float* __restrict__ Ktk)
{
    const int wave = threadIdx.x >> 6;
    const int lane = threadIdx.x & 63;
    const int half = lane >> 5;
    const int L    = lane & 31;
    const int gw   = (blockIdx.x * 4 + wave) * 2 + half;   // 0..32767
    const int mat  = gw >> 14;                             // 0: Q, 1: K
    const int row  = gw & 16383;
    const float* src = ((mat == 0) ? Qb : Kb) + (size_t)row * HW_;
    float* dst       = ((mat == 0) ? Qtk : Ktk) + (size_t)row * KTOP;

    float v[32];
    if (L < 24) {
        const float4* s4 = (const float4*)(src + L * 32);
#pragma unroll
        for (int q = 0; q < 8; q++) {
            float4 t = s4[q];
            v[q * 4 + 0] = t.x; v[q * 4 + 1] = t.y;
            v[q * 4 + 2] = t.z; v[q * 4 + 3] = t.w;
        }
    } else if (L == 24) {
        const float4* s4 = (const float4*)(src + 768);
#pragma unroll
        for (int q = 0; q < 4; q++) {
            float4 t = s4[q];
            v[q * 4 + 0] = t.x; v[q * 4 + 1] = t.y;
            v[q * 4 + 2] = t.z; v[q * 4 + 3] = t.w;
        }
#pragma unroll
        for (int r = 16; r < 32; r++) v[r] = -FLT_MAX;
    } else {
#pragma unroll
        for (int r = 0; r < 32; r++) v[r] = -FLT_MAX;
    }

    // ---- Phase A: sort each 256-elem block (8 lanes x 32 regs) DESCENDING.
    // Phases k=2..128 are the standard alternating-direction bitonic phases
    // (identical to the full-sort network); k=256 runs with up==1 everywhere
    // so every block ends descending (not alternating).
#pragma unroll
    for (int k = 2; k <= 256; k <<= 1) {
#pragma unroll
        for (int j = k >> 1; j >= 1; j >>= 1) {
            if (j >= 32) {
                const int jl = j >> 5;                      // 1,2,4
                const bool up = (k == 256) ? true : ((L & (k >> 5)) == 0);
                const bool isLower = ((L & jl) == 0);
                const bool keepMax = (up == isLower);
#pragma unroll
                for (int r = 0; r < 32; r++) {
                    float other = __shfl_xor(v[r], jl, 64);
                    float mx = fmaxf(v[r], other);
                    float mn = fminf(v[r], other);
                    v[r] = keepMax ? mx : mn;
                }
            } else {
#pragma unroll
                for (int r = 0; r < 32; r++) {
                    if ((r & j) == 0) {
                        const int rb = r | j;
                        const bool up = (k == 256) ? true
                                      : (k >= 32) ? ((L & (k >> 5)) == 0)
                                                  : ((r & k) == 0);
                        float a = v[r], b = v[rb];
                        float hi = fmaxf(a, b), lo = fminf(a, b);
                        v[r]  = up ? hi : lo;
                        v[rb] = up ? lo : hi;
                    }
                }
            }
        }
    }

    // ---- Two top-k reduction rounds:
    // m=0: pair blocks (xor 15): C = max(A[i], B[255-i]) = top-256 of pair,
    //      bitonic -> 8-pass descending merge.
    // m=1: pair the winners (xor 23), same.
#pragma unroll
    for (int m = 0; m < 2; m++) {
        const int mask = m ? 23 : 15;
        // mirror-max: partner block, reversed (lane-mirror via xor + reg 31-r)
#pragma unroll
        for (int r = 0; r < 16; r++) {
            float a = __shfl_xor(v[31 - r], mask, 64);
            float b = __shfl_xor(v[r],      mask, 64);
            v[r]      = fmaxf(v[r],      a);
            v[31 - r] = fmaxf(v[31 - r], b);
        }
        // bitonic merge of a 256-elem bitonic sequence, descending everywhere
#pragma unroll
        for (int j = 128; j >= 1; j >>= 1) {
            if (j >= 32) {
                const int jl = j >> 5;
                const bool keepMax = ((L & jl) == 0);
#pragma unroll
                for (int r = 0; r < 32; r++) {
                    float other = __shfl_xor(v[r], jl, 64);
                    float mx = fmaxf(v[r], other);
                    float mn = fminf(v[r], other);
                    v[r] = keepMax ? mx : mn;
                }
            } else {
#pragma unroll
                for (int r = 0; r < 32; r++) {
                    if ((r & j) == 0) {
                        const int rb = r | j;
                        float a = v[r], b = v[rb];
                        v[r]  = fmaxf(a, b);
                        v[rb] = fminf(a, b);
                    }
                }
            }
        }
    }

    // top-196 sorted descending: elements 0..195 -> L<6 full, L==6 first 4
    if (L < 6) {
        float4* d4 = (float4*)(dst + L * 32);
#pragma unroll
        for (int q = 0; q < 8; q++) {
            float4 t;
            t.x = v[q * 4 + 0]; t.y = v[q * 4 + 1];
            t.z = v[q * 4 + 2]; t.w = v[q * 4 + 3];
            d4[q] = t;
        }
    } else if (L == 6) {
        float4 t;
        t.x = v[0]; t.y = v[1]; t.z = v[2]; t.w = v[3];
        *(float4*)(dst + 192) = t;
    }
}

// ---------------------------------------------------------------------------
// Kernel 3: corr + softmax (unchanged).
// ---------------------------------------------------------------------------
__global__ __launch_bounds__(256) void corr_softmax(
    const float* __restrict__ Qtk, const float* __restrict__ Ktk,
    float* __restrict__ attn)
{
    const int n = blockIdx.x;
    __shared__ float qs[T_ * KTOP];
    __shared__ float ks[T_ * KTOP];
    __shared__ float cm[T_][T_ + 1];
    __shared__ float mx[T_], sm[T_];
    const int tid = threadIdx.x;

    for (int i = tid; i < T_ * KTOP; i += 256) {
        qs[i] = Qtk[(size_t)n * T_ * KTOP + i];
        ks[i] = Ktk[(size_t)n * T_ * KTOP + i];
    }
    __syncthreads();

    const int t = tid >> 4, sidx = tid & 15;
    const float* qr = &qs[t * KTOP];
    const float* kr = &ks[sidx * KTOP];
    float c = 0.f;
#pragma unroll 4
    for (int i = 0; i < KTOP; i++) c += qr[i] * kr[i];
    cm[t][sidx] = c;
    __syncthreads();

    if (tid < T_) {
        float m = cm[tid][0];
        for (int i = 1; i < T_; i++) m = fmaxf(m, cm[tid][i]);
        mx[tid] = m;
    }
    __syncthreads();
    float e = expf(c - mx[t]);
    cm[t][sidx] = e;
    __syncthreads();
    if (tid < T_) {
        float ssum = 0.f;
        for (int i = 0; i < T_; i++) ssum += cm[tid][i];
        sm[tid] = ssum;
    }
    __syncthreads();
    attn[(size_t)n * 256 + tid] = e / sm[t];
}

// ---------------------------------------------------------------------------
// Kernel 4: apply attention, output TRANSPOSED bf16: yT[b][t*784+p][cr].
// grid (49, 8): (p-window of 16, batch). cr processed in chunks of 16.
// ---------------------------------------------------------------------------
__global__ __launch_bounds__(256) void apply_attn_T(
    const float* __restrict__ attn, const float* __restrict__ V,
    unsigned short* __restrict__ yT)
{
    const int pc = blockIdx.x;      // p-window
    const int b  = blockIdx.y;
    const int p0 = pc * 16;
    const int tid = threadIdx.x;
    const int crl = tid & 15;       // local cr
    const int g   = tid >> 4;       // t index (0..15)

    __shared__ float at[16][257];   // [crl][t*16+s]
    __shared__ float vt[16][260];   // [crl][s*16+p], 16B-aligned rows

    for (int chunk = 0; chunk < 8; chunk++) {
        const int crbase = chunk * 16;
        for (int i = tid; i < 16 * 256; i += 256) {
            int cr = i >> 8, ts = i & 255;
            at[cr][ts] = attn[((size_t)(b * 128 + crbase + cr)) * 256 + ts];
        }
        for (int i = tid; i < 16 * 256; i += 256) {
            int cr = i >> 8, s = (i >> 4) & 15, p = i & 15;
            vt[cr][s * 16 + p] =
                V[((size_t)(b * 128 + crbase + cr)) * THW_ + s * HW_ + p0 + p];
        }
        __syncthreads();

        const int cr = crbase + crl;
        float a[16];
#pragma unroll
        for (int s = 0; s < 16; s++) a[s] = at[crl][g * 16 + s];
        float sum[16];
#pragma unroll
        for (int p = 0; p < 16; p++) sum[p] = 0.f;
#pragma unroll
        for (int s = 0; s < 16; s++) {
            const float as = a[s];
#pragma unroll
            for (int p4 = 0; p4 < 4; p4++) {
                float4 vv = *(const float4*)&vt[crl][s * 16 + p4 * 4];
                sum[p4 * 4 + 0] += as * vv.x;
                sum[p4 * 4 + 1] += as * vv.y;
                sum[p4 * 4 + 2] += as * vv.z;
                sum[p4 * 4 + 3] += as * vv.w;
            }
        }
        const size_t obase = (size_t)b * THW_ + (size_t)g * HW_ + p0;
#pragma unroll
        for (int p = 0; p < 16; p++)
            yT[(obase + p) * 128 + cr] = f2bf(sum[p]);
        __syncthreads();
    }
}

// ---------------------------------------------------------------------------
// Kernel 5: reconstruct GEMM via bf16 MFMA, fused BN + residual (v2.1,
// unchanged from r10's measured version).
// grid (196, 2, 8): (p-tile, co-half, batch)
// ---------------------------------------------------------------------------
__global__ __launch_bounds__(256, 3) void gemm_recon_mfma(
    const unsigned short* __restrict__ Wrbf, const unsigned short* __restrict__ yT,
    const float* __restrict__ A1, const float* __restrict__ A2,
    const float* __restrict__ x, float* __restrict__ out)
{
    const int tid  = threadIdx.x;
    const int wave = tid >> 6;
    const int lane = tid & 63;
    const int quad = lane >> 4;
    const int l16  = lane & 15;
    const int p0   = blockIdx.x * 64;
    const int coB  = blockIdx.y * 128;
    const int b    = blockIdx.z;
    const int mW   = wave * 32;

    __shared__ unsigned short Wld[128][136];   // 272B rows (17x16B)
    __shared__ unsigned short Yld[64][136];

    // stage Wrbf half: 128 rows x 128 shorts = 32KB = 2048 uint4
    // (16 uint4 per row: row = c>>4, part = c&15)
#pragma unroll
    for (int it = 0; it < 8; it++) {
        int c = tid + it * 256, row = c >> 4, part = c & 15;
        *(uint4*)&Wld[row][part * 8] =
            *(const uint4*)&Wrbf[(size_t)(coB + row) * 128 + part * 8];
    }
    // stage yT tile: 64 contiguous thw-rows x 128 shorts = 16KB (1024 uint4)
    const unsigned short* yTb = yT + ((size_t)b * THW_ + p0) * 128;
#pragma unroll
    for (int it = 0; it < 4; it++) {
        int c = tid + it * 256, row = c >> 4, part = c & 15;
        *(uint4*)&Yld[row][part * 8] =
            *(const uint4*)&yTb[(size_t)row * 128 + part * 8];
    }
    __syncthreads();

    float4_ acc[2][4];
#pragma unroll
    for (int i = 0; i < 2; i++)
#pragma unroll
        for (int j = 0; j < 4; j++) acc[i][j] = (float4_)0.f;

#pragma unroll
    for (int k0 = 0; k0 < 128; k0 += 32) {
        short8 Bf[4];
#pragma unroll
        for (int nf = 0; nf < 4; nf++)
            Bf[nf] = *(const short8*)&Yld[nf * 16 + l16][k0 + quad * 8];
#pragma unroll
        for (int mf = 0; mf < 2; mf++) {
            short8 Af = *(const short8*)&Wld[mW + mf * 16 + l16][k0 + quad * 8];
#pragma unroll
            for (int nf = 0; nf < 4; nf++)
                acc[mf][nf] = __builtin_amdgcn_mfma_f32_16x16x32_bf16(Af, Bf[nf], acc[mf][nf], 0, 0, 0);
        }
    }

#pragma unroll
    for (int mf = 0; mf < 2; mf++) {
#pragma unroll
        for (int r = 0; r < 4; r++) {
            int co = coB + mW + mf * 16 + quad * 4 + r;
            float sc = A1[co], sh = A2[co];
            size_t base = ((size_t)b * 256 + co) * THW_ + p0 + l16;
#pragma unroll
            for (int nf = 0; nf < 4; nf++) {
                float xv = x[base + nf * 16];
                out[base + nf * 16] = acc[mf][nf][r] * sc + sh + xv;
            }
        }
    }
}

// ---------------------------------------------------------------------------
extern "C" void kernel_launch(void* const* d_in, const int* in_sizes, int n_in,
                              void* d_out, int out_size, void* d_ws, size_t ws_size,
                              hipStream_t stream)
{
    const float* x      = (const float*)d_in[0];
    const float* Wq     = (const float*)d_in[1];
    const float* bq     = (const float*)d_in[2];
    const float* Wk     = (const float*)d_in[3];
    const float* bk     = (const float*)d_in[4];
    const float* Wv     = (const float*)d_in[5];
    const float* bv     = (const float*)d_in[6];
    const float* Wr     = (const float*)d_in[7];
    const float* br     = (const float*)d_in[8];
    const float* gamma  = (const float*)d_in[9];
    const float* beta   = (const float*)d_in[10];
    const float* bn_mean= (const float*)d_in[11];
    const float* bn_var = (const float*)d_in[12];
    float* out = (float*)d_out;

    // d_out doubles as scratch for Q and K (exactly 2 * N_*THW_ floats)
    float* Qb = out;
    float* Kb = out + (size_t)N_ * THW_;

    // workspace layout
    char* ws = (char*)d_ws;
    float* Vb            = (float*)ws;                       ws += (size_t)N_ * THW_ * 4;      // 51.4 MB
    unsigned short* yT   = (unsigned short*)ws;              ws += (size_t)N_ * THW_ * 2;      // 25.7 MB
    float* Qtk           = (float*)ws;                       ws += (size_t)N_ * T_ * KTOP * 4;
    float* Ktk           = (float*)ws;                       ws += (size_t)N_ * T_ * KTOP * 4;
    float* attn          = (float*)ws;                       ws += (size_t)N_ * T_ * T_ * 4;
    unsigned short* W16  = (unsigned short*)ws;              ws += 384 * 256 * 2;
    unsigned short* Wrbf = (unsigned short*)ws;              ws += 256 * 128 * 2;
    float* bias3         = (float*)ws;                       ws += 384 * 4;
    float* A1            = (float*)ws;                       ws += 256 * 4;
    float* A2            = (float*)ws;                       ws += 256 * 4;

    prep<<<dim3(384), 256, 0, stream>>>(Wq, Wk, Wv, Wr, bq, bk, bv, br,
                                        gamma, beta, bn_mean, bn_var,
                                        W16, Wrbf, bias3, A1, A2);
    gemm_qkv_mfma<<<dim3(196, 8), 512, 0, stream>>>(W16, x, bias3, Qb, Kb, Vb);
    topk_sort_wave<<<dim3(4096), 256, 0, stream>>>(Qb, Kb, Qtk, Ktk);
    corr_softmax<<<dim3(1024), 256, 0, stream>>>(Qtk, Ktk, attn);
    apply_attn_T<<<dim3(49, 8), 256, 0, stream>>>(attn, Vb, yT);
    gemm_recon_mfma<<<dim3(196, 2, 8), 256, 0, stream>>>(Wrbf, yT, A1, A2, x, out);
}

// Round 12
// 467.561 us; speedup vs baseline: 1.2754x; 1.0342x over previous
//
#include <hip/hip_runtime.h>
#include <hip/hip_bf16.h>
#include <cfloat>

// Problem constants
#define B_   8
#define C_   256
#define CR_  128
#define T_   16
#define HW_  784
#define THW_ 12544           // T_*HW_
#define N_   1024            // B_*CR_
#define KTOP 196

typedef __attribute__((ext_vector_type(8))) short short8;
typedef __attribute__((ext_vector_type(8))) _Float16 half8;
typedef __attribute__((ext_vector_type(4))) float float4_;

// bf16 helpers (RN-even), header-independent
__device__ __forceinline__ unsigned short f2bf(float x) {
    unsigned int u = __float_as_uint(x);
    unsigned int r = u + 0x7fffu + ((u >> 16) & 1u);
    return (unsigned short)(r >> 16);
}
__device__ __forceinline__ float bf2f(unsigned short s) {
    return __uint_as_float(((unsigned int)s) << 16);
}
// fp16 split: v = hi + lo to 22 mantissa bits
__device__ __forceinline__ void splith(float v, unsigned short& h, unsigned short& l) {
    _Float16 hh = (_Float16)v;
    _Float16 ll = (_Float16)(v - (float)hh);
    h = __builtin_bit_cast(unsigned short, hh);
    l = __builtin_bit_cast(unsigned short, ll);
}

// ---------------------------------------------------------------------------
// Kernel 0: prep.
//  - W16  [o=384][k=256] fp16 of {Wq,Wk,Wv} (native k-major)
//  - Wrbf [co=256][cr=128] bf16 of Wr (native k-major)
//  - bias3[384] = bq|bk|bv
//  - A1[co]=gamma*rsqrt(var+eps), A2[co]=br*A1 + beta - mean*A1
// ---------------------------------------------------------------------------
__global__ __launch_bounds__(256) void prep(
    const float* __restrict__ Wq, const float* __restrict__ Wk,
    const float* __restrict__ Wv, const float* __restrict__ Wr,
    const float* __restrict__ bq, const float* __restrict__ bk,
    const float* __restrict__ bv, const float* __restrict__ br,
    const float* __restrict__ gamma, const float* __restrict__ beta,
    const float* __restrict__ bn_mean, const float* __restrict__ bn_var,
    unsigned short* __restrict__ W16,
    unsigned short* __restrict__ Wrbf, float* __restrict__ bias3,
    float* __restrict__ A1, float* __restrict__ A2)
{
    int idx = blockIdx.x * 256 + threadIdx.x;
    if (idx < 384 * 256) {
        int o = idx >> 8, k = idx & 255;
        int m = o >> 7, r = o & 127;
        const float* W = (m == 0) ? Wq : (m == 1) ? Wk : Wv;
        float v = W[r * 256 + k];
        _Float16 hh = (_Float16)v;
        W16[idx] = __builtin_bit_cast(unsigned short, hh);
    }
    if (idx < 256 * 128) {
        Wrbf[idx] = f2bf(Wr[idx]);
    }
    if (idx < 384) {
        bias3[idx] = (idx < 128) ? bq[idx] : (idx < 256) ? bk[idx - 128] : bv[idx - 256];
    }
    if (idx < 256) {
        float sc = gamma[idx] * rsqrtf(bn_var[idx] + 1e-5f);
        A1[idx] = sc;
        A2[idx] = br[idx] * sc + beta[idx] - bn_mean[idx] * sc;
    }
}

// ---------------------------------------------------------------------------
// Kernel 1: QKV GEMM via fp16x2 MFMA (unchanged from r11's measured version:
// 123us, 243MB @ 1.97 TB/s, MfmaUtil 12.6 / VALUBusy 11.5 / occ 34 —
// latency-bound; occupancy experiment deferred to next round).
// grid (196, 8): (p-tile of 64, batch)
// ---------------------------------------------------------------------------
__global__ __launch_bounds__(512, 4) void gemm_qkv_mfma(
    const unsigned short* __restrict__ W16,
    const float* __restrict__ x, const float* __restrict__ bias3,
    float* __restrict__ Qb, float* __restrict__ Kb, float* __restrict__ Vb)
{
    const int tid  = threadIdx.x;
    const int wave = tid >> 6;
    const int lane = tid & 63;
    const int quad = lane >> 4;
    const int l16  = lane & 15;
    const int p0   = blockIdx.x * 64;
    const int b    = blockIdx.y;
    const int mW   = wave * 48;

    // A: [buf][row=384][k=32, 72B rows]; B: [buf][var hi/lo][p=64][k=32 pad->40]
    __shared__ unsigned short Ald[2][384][36];
    __shared__ unsigned short Bld[2][2][64][40];

    float4_ acc[3][4];
#pragma unroll
    for (int i = 0; i < 3; i++)
#pragma unroll
        for (int j = 0; j < 4; j++) acc[i][j] = (float4_)0.f;

    const float* xb = x + (size_t)b * C_ * THW_;
    const int sp  = lane;        // staged p (coalesced across lanes)
    const int kgB = wave * 4;    // staged k-group for B (4 k per thread)

    // prologue: stage k-step 0 into buf 0
    {
#pragma unroll
        for (int it = 0; it < 6; it++) {
            int c = tid + it * 512, row = c >> 3, part = c & 7;
            *(uint2*)&Ald[0][row][part * 4] =
                *(const uint2*)&W16[(size_t)row * 256 + part * 4];
        }
        float f[4];
#pragma unroll
        for (int j = 0; j < 4; j++)
            f[j] = xb[(size_t)(kgB + j) * THW_ + p0 + sp];
#pragma unroll
        for (int j = 0; j < 4; j++) {
            unsigned short hh, ll; splith(f[j], hh, ll);
            Bld[0][0][sp][kgB + j] = hh;
            Bld[0][1][sp][kgB + j] = ll;
        }
    }
    __syncthreads();

#pragma unroll 2
    for (int ks = 0; ks < 8; ks++) {
        const int cur = ks & 1;
        const int k0n = (ks + 1) * 32;

        // issue next-step global loads early (latency hides under MFMA)
        uint2 au[6];
        float f[4];
        if (ks < 7) {
#pragma unroll
            for (int it = 0; it < 6; it++) {
                int c = tid + it * 512, row = c >> 3, part = c & 7;
                au[it] = *(const uint2*)&W16[(size_t)row * 256 + k0n + part * 4];
            }
#pragma unroll
            for (int j = 0; j < 4; j++)
                f[j] = xb[(size_t)(k0n + kgB + j) * THW_ + p0 + sp];
        }

        // B fragments from LDS (split already done)
        short8 Bh[4], Bl[4];
#pragma unroll
        for (int nf = 0; nf < 4; nf++) {
            Bh[nf] = *(const short8*)&Bld[cur][0][nf * 16 + l16][quad * 8];
            Bl[nf] = *(const short8*)&Bld[cur][1][nf * 16 + l16][quad * 8];
        }

        // MFMA: 3 m-frags x 4 n-frags x 2 products (fp16x2)
#pragma unroll
        for (int mf = 0; mf < 3; mf++) {
            const unsigned short* ap = &Ald[cur][mW + mf * 16 + l16][quad * 8];
            half8 Af;
            *(uint2*)&Af       = *(const uint2*)ap;        // shorts 0..3
            *((uint2*)&Af + 1) = *(const uint2*)(ap + 4);  // shorts 4..7
#pragma unroll
            for (int nf = 0; nf < 4; nf++) {
                acc[mf][nf] = __builtin_amdgcn_mfma_f32_16x16x32_f16(
                    Af, *(const half8*)&Bl[nf], acc[mf][nf], 0, 0, 0);
                acc[mf][nf] = __builtin_amdgcn_mfma_f32_16x16x32_f16(
                    Af, *(const half8*)&Bh[nf], acc[mf][nf], 0, 0, 0);
            }
        }

        // write next tile into the other buffer (waits on the early loads)
        if (ks < 7) {
#pragma unroll
            for (int it = 0; it < 6; it++) {
                int c = tid + it * 512, row = c >> 3, part = c & 7;
                *(uint2*)&Ald[cur ^ 1][row][part * 4] = au[it];
            }
#pragma unroll
            for (int j = 0; j < 4; j++) {
                unsigned short hh, ll; splith(f[j], hh, ll);
                Bld[cur ^ 1][0][sp][kgB + j] = hh;
                Bld[cur ^ 1][1][sp][kgB + j] = ll;
            }
        }
        __syncthreads();
    }

    // --- epilogue: o = mW + mf*16 + quad*4 + r, p = p0 + nf*16 + l16 ---
#pragma unroll
    for (int mf = 0; mf < 3; mf++) {
#pragma unroll
        for (int r = 0; r < 4; r++) {
            int oo  = mW + mf * 16 + quad * 4 + r;
            int mat = oo >> 7;
            int cr  = oo & 127;
            float bi = bias3[oo];
            float* dst = ((mat == 0) ? Qb : (mat == 1) ? Kb : Vb)
                         + ((size_t)(b * 128 + cr)) * THW_ + p0 + l16;
#pragma unroll
            for (int nf = 0; nf < 4; nf++)
                dst[nf * 16] = acc[mf][nf][r] + bi;
        }
    }
}

// ---------------------------------------------------------------------------
// Kernel 2: per-row top-196 via BITONIC TOP-K (v3, unchanged — measured
// improvement 137 -> ~<123; near its pass-count floor in this framework).
// ---------------------------------------------------------------------------
__global__ __launch_bounds__(256) void topk_sort_wave(
    const float* __restrict__ Qb, const float* __restrict__ Kb,
    float* __restrict__ Qtk, float* __restrict__ Ktk)
{
    const int wave = threadIdx.x >> 6;
    const int lane = threadIdx.x & 63;
    const int half = lane >> 5;
    const int L    = lane & 31;
    const int gw   = (blockIdx.x * 4 + wave) * 2 + half;   // 0..32767
    const int mat  = gw >> 14;                             // 0: Q, 1: K
    const int row  = gw & 16383;
    const float* src = ((mat == 0) ? Qb : Kb) + (size_t)row * HW_;
    float* dst       = ((mat == 0) ? Qtk : Ktk) + (size_t)row * KTOP;

    float v[32];
    if (L < 24) {
        const float4* s4 = (const float4*)(src + L * 32);
#pragma unroll
        for (int q = 0; q < 8; q++) {
            float4 t = s4[q];
            v[q * 4 + 0] = t.x; v[q * 4 + 1] = t.y;
            v[q * 4 + 2] = t.z; v[q * 4 + 3] = t.w;
        }
    } else if (L == 24) {
        const float4* s4 = (const float4*)(src + 768);
#pragma unroll
        for (int q = 0; q < 4; q++) {
            float4 t = s4[q];
            v[q * 4 + 0] = t.x; v[q * 4 + 1] = t.y;
            v[q * 4 + 2] = t.z; v[q * 4 + 3] = t.w;
        }
#pragma unroll
        for (int r = 16; r < 32; r++) v[r] = -FLT_MAX;
    } else {
#pragma unroll
        for (int r = 0; r < 32; r++) v[r] = -FLT_MAX;
    }

    // ---- Phase A: sort each 256-elem block (8 lanes x 32 regs) DESCENDING.
#pragma unroll
    for (int k = 2; k <= 256; k <<= 1) {
#pragma unroll
        for (int j = k >> 1; j >= 1; j >>= 1) {
            if (j >= 32) {
                const int jl = j >> 5;                      // 1,2,4
                const bool up = (k == 256) ? true : ((L & (k >> 5)) == 0);
                const bool isLower = ((L & jl) == 0);
                const bool keepMax = (up == isLower);
#pragma unroll
                for (int r = 0; r < 32; r++) {
                    float other = __shfl_xor(v[r], jl, 64);
                    float mx = fmaxf(v[r], other);
                    float mn = fminf(v[r], other);
                    v[r] = keepMax ? mx : mn;
                }
            } else {
#pragma unroll
                for (int r = 0; r < 32; r++) {
                    if ((r & j) == 0) {
                        const int rb = r | j;
                        const bool up = (k == 256) ? true
                                      : (k >= 32) ? ((L & (k >> 5)) == 0)
                                                  : ((r & k) == 0);
                        float a = v[r], b = v[rb];
                        float hi = fmaxf(a, b), lo = fminf(a, b);
                        v[r]  = up ? hi : lo;
                        v[rb] = up ? lo : hi;
                    }
                }
            }
        }
    }

    // ---- Two top-k reduction rounds (mirror-max keep-256 + 8-pass merge).
#pragma unroll
    for (int m = 0; m < 2; m++) {
        const int mask = m ? 23 : 15;
#pragma unroll
        for (int r = 0; r < 16; r++) {
            float a = __shfl_xor(v[31 - r], mask, 64);
            float b = __shfl_xor(v[r],      mask, 64);
            v[r]      = fmaxf(v[r],      a);
            v[31 - r] = fmaxf(v[31 - r], b);
        }
#pragma unroll
        for (int j = 128; j >= 1; j >>= 1) {
            if (j >= 32) {
                const int jl = j >> 5;
                const bool keepMax = ((L & jl) == 0);
#pragma unroll
                for (int r = 0; r < 32; r++) {
                    float other = __shfl_xor(v[r], jl, 64);
                    float mx = fmaxf(v[r], other);
                    float mn = fminf(v[r], other);
                    v[r] = keepMax ? mx : mn;
                }
            } else {
#pragma unroll
                for (int r = 0; r < 32; r++) {
                    if ((r & j) == 0) {
                        const int rb = r | j;
                        float a = v[r], b = v[rb];
                        v[r]  = fmaxf(a, b);
                        v[rb] = fminf(a, b);
                    }
                }
            }
        }
    }

    // top-196 sorted descending: elements 0..195 -> L<6 full, L==6 first 4
    if (L < 6) {
        float4* d4 = (float4*)(dst + L * 32);
#pragma unroll
        for (int q = 0; q < 8; q++) {
            float4 t;
            t.x = v[q * 4 + 0]; t.y = v[q * 4 + 1];
            t.z = v[q * 4 + 2]; t.w = v[q * 4 + 3];
            d4[q] = t;
        }
    } else if (L == 6) {
        float4 t;
        t.x = v[0]; t.y = v[1]; t.z = v[2]; t.w = v[3];
        *(float4*)(dst + 192) = t;
    }
}

// ---------------------------------------------------------------------------
// Kernel 3: corr + softmax (unchanged).
// ---------------------------------------------------------------------------
__global__ __launch_bounds__(256) void corr_softmax(
    const float* __restrict__ Qtk, const float* __restrict__ Ktk,
    float* __restrict__ attn)
{
    const int n = blockIdx.x;
    __shared__ float qs[T_ * KTOP];
    __shared__ float ks[T_ * KTOP];
    __shared__ float cm[T_][T_ + 1];
    __shared__ float mx[T_], sm[T_];
    const int tid = threadIdx.x;

    for (int i = tid; i < T_ * KTOP; i += 256) {
        qs[i] = Qtk[(size_t)n * T_ * KTOP + i];
        ks[i] = Ktk[(size_t)n * T_ * KTOP + i];
    }
    __syncthreads();

    const int t = tid >> 4, sidx = tid & 15;
    const float* qr = &qs[t * KTOP];
    const float* kr = &ks[sidx * KTOP];
    float c = 0.f;
#pragma unroll 4
    for (int i = 0; i < KTOP; i++) c += qr[i] * kr[i];
    cm[t][sidx] = c;
    __syncthreads();

    if (tid < T_) {
        float m = cm[tid][0];
        for (int i = 1; i < T_; i++) m = fmaxf(m, cm[tid][i]);
        mx[tid] = m;
    }
    __syncthreads();
    float e = expf(c - mx[t]);
    cm[t][sidx] = e;
    __syncthreads();
    if (tid < T_) {
        float ssum = 0.f;
        for (int i = 0; i < T_; i++) ssum += cm[tid][i];
        sm[tid] = ssum;
    }
    __syncthreads();
    attn[(size_t)n * 256 + tid] = e / sm[t];
}

// ---------------------------------------------------------------------------
// Kernel 4: apply attention, output TRANSPOSED bf16: yT[b][t*784+p][cr].
//
// v2: chunk loop moved to gridDim.z (was 8 SERIAL chunks per block with only
// 392 blocks = 1.5 blocks/CU / 6 waves/CU — L3 staging latency fully exposed;
// inferred ~100-120us, 2nd-largest kernel). Chunks share NO data and write
// disjoint cr columns -> zero extra traffic, no races. 3136 blocks,
// 4 blocks/CU by LDS (33KB) = 16 waves/CU.
// grid (49, 8, 8): (p-window of 16, batch, cr-chunk of 16)
// ---------------------------------------------------------------------------
__global__ __launch_bounds__(256) void apply_attn_T(
    const float* __restrict__ attn, const float* __restrict__ V,
    unsigned short* __restrict__ yT)
{
    const int pc = blockIdx.x;          // p-window
    const int b  = blockIdx.y;
    const int crbase = blockIdx.z * 16; // cr-chunk
    const int p0 = pc * 16;
    const int tid = threadIdx.x;
    const int crl = tid & 15;           // local cr
    const int g   = tid >> 4;           // t index (0..15)

    __shared__ float at[16][257];   // [crl][t*16+s]
    __shared__ float vt[16][260];   // [crl][s*16+p], 16B-aligned rows

    for (int i = tid; i < 16 * 256; i += 256) {
        int cr = i >> 8, ts = i & 255;
        at[cr][ts] = attn[((size_t)(b * 128 + crbase + cr)) * 256 + ts];
    }
    for (int i = tid; i < 16 * 256; i += 256) {
        int cr = i >> 8, s = (i >> 4) & 15, p = i & 15;
        vt[cr][s * 16 + p] =
            V[((size_t)(b * 128 + crbase + cr)) * THW_ + s * HW_ + p0 + p];
    }
    __syncthreads();

    const int cr = crbase + crl;
    float a[16];
#pragma unroll
    for (int s = 0; s < 16; s++) a[s] = at[crl][g * 16 + s];
    float sum[16];
#pragma unroll
    for (int p = 0; p < 16; p++) sum[p] = 0.f;
#pragma unroll
    for (int s = 0; s < 16; s++) {
        const float as = a[s];
#pragma unroll
        for (int p4 = 0; p4 < 4; p4++) {
            float4 vv = *(const float4*)&vt[crl][s * 16 + p4 * 4];
            sum[p4 * 4 + 0] += as * vv.x;
            sum[p4 * 4 + 1] += as * vv.y;
            sum[p4 * 4 + 2] += as * vv.z;
            sum[p4 * 4 + 3] += as * vv.w;
        }
    }
    const size_t obase = (size_t)b * THW_ + (size_t)g * HW_ + p0;
#pragma unroll
    for (int p = 0; p < 16; p++)
        yT[(obase + p) * 128 + cr] = f2bf(sum[p]);
}

// ---------------------------------------------------------------------------
// Kernel 5: reconstruct GEMM via bf16 MFMA, fused BN + residual (v2.1,
// unchanged from r10/r11's measured version).
// grid (196, 2, 8): (p-tile, co-half, batch)
// ---------------------------------------------------------------------------
__global__ __launch_bounds__(256, 3) void gemm_recon_mfma(
    const unsigned short* __restrict__ Wrbf, const unsigned short* __restrict__ yT,
    const float* __restrict__ A1, const float* __restrict__ A2,
    const float* __restrict__ x, float* __restrict__ out)
{
    const int tid  = threadIdx.x;
    const int wave = tid >> 6;
    const int lane = tid & 63;
    const int quad = lane >> 4;
    const int l16  = lane & 15;
    const int p0   = blockIdx.x * 64;
    const int coB  = blockIdx.y * 128;
    const int b    = blockIdx.z;
    const int mW   = wave * 32;

    __shared__ unsigned short Wld[128][136];   // 272B rows (17x16B)
    __shared__ unsigned short Yld[64][136];

    // stage Wrbf half: 128 rows x 128 shorts = 32KB = 2048 uint4
    // (16 uint4 per row: row = c>>4, part = c&15)
#pragma unroll
    for (int it = 0; it < 8; it++) {
        int c = tid + it * 256, row = c >> 4, part = c & 15;
        *(uint4*)&Wld[row][part * 8] =
            *(const uint4*)&Wrbf[(size_t)(coB + row) * 128 + part * 8];
    }
    // stage yT tile: 64 contiguous thw-rows x 128 shorts = 16KB (1024 uint4)
    const unsigned short* yTb = yT + ((size_t)b * THW_ + p0) * 128;
#pragma unroll
    for (int it = 0; it < 4; it++) {
        int c = tid + it * 256, row = c >> 4, part = c & 15;
        *(uint4*)&Yld[row][part * 8] =
            *(const uint4*)&yTb[(size_t)row * 128 + part * 8];
    }
    __syncthreads();

    float4_ acc[2][4];
#pragma unroll
    for (int i = 0; i < 2; i++)
#pragma unroll
        for (int j = 0; j < 4; j++) acc[i][j] = (float4_)0.f;

#pragma unroll
    for (int k0 = 0; k0 < 128; k0 += 32) {
        short8 Bf[4];
#pragma unroll
        for (int nf = 0; nf < 4; nf++)
            Bf[nf] = *(const short8*)&Yld[nf * 16 + l16][k0 + quad * 8];
#pragma unroll
        for (int mf = 0; mf < 2; mf++) {
            short8 Af = *(const short8*)&Wld[mW + mf * 16 + l16][k0 + quad * 8];
#pragma unroll
            for (int nf = 0; nf < 4; nf++)
                acc[mf][nf] = __builtin_amdgcn_mfma_f32_16x16x32_bf16(Af, Bf[nf], acc[mf][nf], 0, 0, 0);
        }
    }

#pragma unroll
    for (int mf = 0; mf < 2; mf++) {
#pragma unroll
        for (int r = 0; r < 4; r++) {
            int co = coB + mW + mf * 16 + quad * 4 + r;
            float sc = A1[co], sh = A2[co];
            size_t base = ((size_t)b * 256 + co) * THW_ + p0 + l16;
#pragma unroll
            for (int nf = 0; nf < 4; nf++) {
                float xv = x[base + nf * 16];
                out[base + nf * 16] = acc[mf][nf][r] * sc + sh + xv;
            }
        }
    }
}

// ---------------------------------------------------------------------------
extern "C" void kernel_launch(void* const* d_in, const int* in_sizes, int n_in,
                              void* d_out, int out_size, void* d_ws, size_t ws_size,
                              hipStream_t stream)
{
    const float* x      = (const float*)d_in[0];
    const float* Wq     = (const float*)d_in[1];
    const float* bq     = (const float*)d_in[2];
    const float* Wk     = (const float*)d_in[3];
    const float* bk     = (const float*)d_in[4];
    const float* Wv     = (const float*)d_in[5];
    const float* bv     = (const float*)d_in[6];
    const float* Wr     = (const float*)d_in[7];
    const float* br     = (const float*)d_in[8];
    const float* gamma  = (const float*)d_in[9];
    const float* beta   = (const float*)d_in[10];
    const float* bn_mean= (const float*)d_in[11];
    const float* bn_var = (const float*)d_in[12];
    float* out = (float*)d_out;

    // d_out doubles as scratch for Q and K (exactly 2 * N_*THW_ floats)
    float* Qb = out;
    float* Kb = out + (size_t)N_ * THW_;

    // workspace layout
    char* ws = (char*)d_ws;
    float* Vb            = (float*)ws;                       ws += (size_t)N_ * THW_ * 4;      // 51.4 MB
    unsigned short* yT   = (unsigned short*)ws;              ws += (size_t)N_ * THW_ * 2;      // 25.7 MB
    float* Qtk           = (float*)ws;                       ws += (size_t)N_ * T_ * KTOP * 4;
    float* Ktk           = (float*)ws;                       ws += (size_t)N_ * T_ * KTOP * 4;
    float* attn          = (float*)ws;                       ws += (size_t)N_ * T_ * T_ * 4;
    unsigned short* W16  = (unsigned short*)ws;              ws += 384 * 256 * 2;
    unsigned short* Wrbf = (unsigned short*)ws;              ws += 256 * 128 * 2;
    float* bias3         = (float*)ws;                       ws += 384 * 4;
    float* A1            = (float*)ws;                       ws += 256 * 4;
    float* A2            = (float*)ws;                       ws += 256 * 4;

    prep<<<dim3(384), 256, 0, stream>>>(Wq, Wk, Wv, Wr, bq, bk, bv, br,
                                        gamma, beta, bn_mean, bn_var,
                                        W16, Wrbf, bias3, A1, A2);
    gemm_qkv_mfma<<<dim3(196, 8), 512, 0, stream>>>(W16, x, bias3, Qb, Kb, Vb);
    topk_sort_wave<<<dim3(4096), 256, 0, stream>>>(Qb, Kb, Qtk, Ktk);
    corr_softmax<<<dim3(1024), 256, 0, stream>>>(Qtk, Ktk, attn);
    apply_attn_T<<<dim3(49, 8, 8), 256, 0, stream>>>(attn, Vb, yT);
    gemm_recon_mfma<<<dim3(196, 2, 8), 256, 0, stream>>>(Wrbf, yT, A1, A2, x, out);
}